// Round 4
// baseline (643.733 us; speedup 1.0000x reference)
//
#include <hip/hip_runtime.h>

#define HH 16
#define DD 64
#define BBATCH 4
#define NSEQ 2048
#define CDIM 1024
#define EPSLN 1e-6f

typedef __bf16 bf16x8 __attribute__((ext_vector_type(8)));
typedef float f32x4 __attribute__((ext_vector_type(4)));
typedef short s16x4 __attribute__((ext_vector_type(4)));
typedef short s16x8 __attribute__((ext_vector_type(8)));
typedef unsigned short u16;

__device__ inline u16 f2b(float f) {  // RNE
  unsigned u = __builtin_bit_cast(unsigned, f);
  u += 0x7fffu + ((u >> 16) & 1u);
  return (u16)(u >> 16);
}
// pack 2 floats -> 2 bf16 (round-half-up; cheap: 5 VALU ops)
__device__ inline unsigned pack2(float a, float b) {
  unsigned ua = __builtin_bit_cast(unsigned, a);
  unsigned ub = __builtin_bit_cast(unsigned, b);
  return ((ua + 0x8000u) >> 16) | ((ub + 0x8000u) & 0xffff0000u);
}
#if __has_builtin(__builtin_amdgcn_exp2f)
#define EXP2(x) __builtin_amdgcn_exp2f(x)
#else
#define EXP2(x) __expf((x)*0.6931471805599453f)
#endif

// 16B-aligned load of 8 bf16 as MFMA fragment (global or LDS)
__device__ inline bf16x8 ld_frag16(const u16* p) {
  s16x8 v = *(const s16x8*)p;
  return __builtin_bit_cast(bf16x8, v);
}
__device__ inline f32x4 mfma16(bf16x8 a, bf16x8 b, f32x4 c) {
  return __builtin_amdgcn_mfma_f32_16x16x32_bf16(a, b, c, 0, 0, 0);
}
// async global->LDS, 16B per lane (dest = wave-uniform base + lane*16)
__device__ inline void async16(const u16* g, u16* l) {
  __builtin_amdgcn_global_load_lds(
      (const __attribute__((address_space(1))) void*)g,
      (__attribute__((address_space(3))) void*)l, 16, 0, 0);
}

// ---------------- convert x -> bf16 ----------------
__global__ void cvt_x(const float* __restrict__ x, u16* __restrict__ xb) {
  long i = ((long)blockIdx.x * 256 + threadIdx.x) * 8;
  float4 a = *(const float4*)(x + i);
  float4 b = *(const float4*)(x + i + 4);
  u16 r[8];
  r[0] = f2b(a.x); r[1] = f2b(a.y); r[2] = f2b(a.z); r[3] = f2b(a.w);
  r[4] = f2b(b.x); r[5] = f2b(b.y); r[6] = f2b(b.z); r[7] = f2b(b.w);
  *(s16x8*)(xb + i) = *(s16x8*)r;
}

// ---------------- transpose + convert weight: w [K][N] f32 -> wT [N][K] bf16 ----------------
__global__ void cvt_wT(const float* __restrict__ w, u16* __restrict__ wT, int K, int N) {
  __shared__ float tile[32][33];
  int nt = N / 32;
  int bn = blockIdx.x % nt, bk = blockIdx.x / nt;
  int tx = threadIdx.x % 32, ty = threadIdx.x / 32;  // ty 0..7
  int k0 = bk * 32, n0 = bn * 32;
  for (int j = 0; j < 4; j++)
    tile[ty + 8 * j][tx] = w[(long)(k0 + ty + 8 * j) * N + n0 + tx];
  __syncthreads();
  for (int j = 0; j < 4; j++)
    wT[(long)(n0 + ty + 8 * j) * K + k0 + tx] = f2b(tile[tx][ty + 8 * j]);
}

// ---------------- GEMM1: qkv = x @ w_qkv + b, fused per-head LN on q/k.
//  q,k -> [B,H,N,D] bf16 (q scaled by D^-0.5 * log2e);  v -> TRANSPOSED [B,H,D,N] bf16
__launch_bounds__(256, 3)
__global__ void gemm_qkv(const u16* __restrict__ A, const u16* __restrict__ BT,
                         const float* __restrict__ bias,
                         const float* __restrict__ gq, const float* __restrict__ gk,
                         u16* __restrict__ qb, u16* __restrict__ kb, u16* __restrict__ vtb) {
  const int Kd = CDIM;
  __shared__ u16 As[128 * 64];
  __shared__ u16 Bs[128 * 64];
  int t = threadIdx.x;
  int lane = t & 63, wave = t >> 6;
  int ln = lane & 15, quad = lane >> 4;
  int bm = blockIdx.x % 64, bn = blockIdx.x / 64;
  int wm = (wave >> 1) * 64, wn = (wave & 1) * 64;
  int r8 = t >> 3;        // 0..31
  int cb = (t & 7) * 8;   // u16 col offset within 64
  const u16* aB = A + (long)(bm * 128) * Kd + cb;
  const u16* bB = BT + (long)(bn * 128) * Kd + cb;
  f32x4 acc[4][4] = {};
  for (int kt = 0; kt < Kd / 64; kt++) {
    __syncthreads();
#pragma unroll
    for (int c = 0; c < 4; c++) {
      int row = c * 32 + r8;
      async16(aB + (long)row * Kd + kt * 64, As + row * 64 + cb);
      async16(bB + (long)row * Kd + kt * 64, Bs + row * 64 + cb);
    }
    __syncthreads();
#pragma unroll
    for (int kk = 0; kk < 2; kk++) {
      bf16x8 af[4], bfv[4];
#pragma unroll
      for (int mt = 0; mt < 4; mt++)
        af[mt] = ld_frag16(As + (wm + mt * 16 + ln) * 64 + kk * 32 + quad * 8);
#pragma unroll
      for (int nt = 0; nt < 4; nt++)
        bfv[nt] = ld_frag16(Bs + (wn + nt * 16 + ln) * 64 + kk * 32 + quad * 8);
#pragma unroll
      for (int mt = 0; mt < 4; mt++)
#pragma unroll
        for (int nt = 0; nt < 4; nt++)
          acc[mt][nt] = mfma16(af[mt], bfv[nt], acc[mt][nt]);
    }
  }
  // ---- epilogue ----
  int tq = bn >> 3;                 // 0=q, 1=k, 2=v (block-uniform)
  int colbase = bn * 128 + wn;      // wave-uniform; spans exactly one head
  int h = (colbase >> 6) & 15;
  int mbase = bm * 128 + wm;
  float bv[4];
#pragma unroll
  for (int nt = 0; nt < 4; nt++) bv[nt] = bias[colbase + nt * 16 + ln];
  if (tq == 2) {
    // V transposed: vtb[((b*H+h)*D + d) * N + n], lane holds 4 consecutive n
#pragma unroll
    for (int mt = 0; mt < 4; mt++) {
      int m0 = mbase + mt * 16 + quad * 4;
      int b = m0 >> 11, n0 = m0 & 2047;
#pragma unroll
      for (int nt = 0; nt < 4; nt++) {
        int d = nt * 16 + ln;
        u16 pk[4];
#pragma unroll
        for (int r = 0; r < 4; r++) pk[r] = f2b(acc[mt][nt][r] + bv[nt]);
        *(s16x4*)(vtb + ((long)((b * HH + h) * DD + d)) * NSEQ + n0) = *(s16x4*)pk;
      }
    }
  } else {
    const float* g = (tq == 0) ? gq : gk;
    // fold softmax scale D^-0.5 AND log2(e) into q so attn uses bare exp2
    float extra = (tq == 0) ? 0.125f * 1.4426950408889634f : 1.0f;
    u16* dst = (tq == 0) ? qb : kb;
    float gv[4];
#pragma unroll
    for (int nt = 0; nt < 4; nt++) gv[nt] = g[nt * 16 + ln] * extra;
#pragma unroll
    for (int mt = 0; mt < 4; mt++)
#pragma unroll
      for (int r = 0; r < 4; r++) {
        float vv[4];
        float s1 = 0.f, s2 = 0.f;
#pragma unroll
        for (int nt = 0; nt < 4; nt++) {
          vv[nt] = acc[mt][nt][r] + bv[nt];
          s1 += vv[nt];
          s2 += vv[nt] * vv[nt];
        }
#pragma unroll
        for (int m = 1; m < 16; m <<= 1) {
          s1 += __shfl_xor(s1, m);
          s2 += __shfl_xor(s2, m);
        }
        float mu = s1 * (1.0f / 64.0f);
        float var = s2 * (1.0f / 64.0f) - mu * mu;
        float rstd = rsqrtf(var + EPSLN);
        int m = mbase + mt * 16 + quad * 4 + r;
        int b = m >> 11, n = m & 2047;
        long base = ((long)((b * HH + h) * NSEQ + n)) * DD;
#pragma unroll
        for (int nt = 0; nt < 4; nt++)
          dst[base + nt * 16 + ln] = f2b((vv[nt] - mu) * rstd * gv[nt]);
      }
  }
}

// ---------------- flash attention v3: barrier-free.
//  S^T = K q^T with K frags from global; exp2; P wave-private in LDS;
//  PV with V^T frags from global ([B,H,D,N] layout). ----------------
__launch_bounds__(256, 4)
__global__ void attn(const u16* __restrict__ qb, const u16* __restrict__ kb,
                     const u16* __restrict__ vtb, u16* __restrict__ ob) {
  __shared__ u16 Pl[4 * 16 * 136];  // per-wave P [q16][k128], row stride 136
  int t = threadIdx.x, lane = t & 63, wave = t >> 6;
  int ln = lane & 15, quad = lane >> 4;
  // XCD swizzle: all 32 q-blocks of one (b,h) on one XCD (blockIdx%8 = XCD)
  int g = blockIdx.x;
  int bh = (g & 7) * 8 + ((g >> 3) & 7);
  int qblk = g >> 6;
  int b = bh >> 4, h = bh & 15;
  const u16* qg = qb + (long)bh * NSEQ * DD;
  const u16* kg = kb + (long)bh * NSEQ * DD;
  const u16* vg = vtb + (long)bh * DD * NSEQ;
  int qrow0 = qblk * 64 + wave * 16;
  bf16x8 bq[2];
#pragma unroll
  for (int kk = 0; kk < 2; kk++)
    bq[kk] = ld_frag16(qg + (long)(qrow0 + ln) * DD + kk * 32 + quad * 8);
  f32x4 o[4] = {};
  float rsum = 0.f;
  u16* Pw = Pl + wave * 16 * 136;
  for (int kv = 0; kv < NSEQ / 128; kv++) {
    // S^T = K(A) x q^T(B): K frags straight from global
    f32x4 st[8];
#pragma unroll
    for (int ct = 0; ct < 8; ct++) {
      const u16* kr = kg + (long)(kv * 128 + ct * 16 + ln) * DD + quad * 8;
      f32x4 z = {};
      z = mfma16(ld_frag16(kr), bq[0], z);
      z = mfma16(ld_frag16(kr + 32), bq[1], z);
      st[ct] = z;
    }
    // p = exp2(s) (log2e folded into q; |s·log2e| <= ~12, exp2 safe in fp32)
#pragma unroll
    for (int ct = 0; ct < 8; ct++) {
      float e0 = EXP2(st[ct][0]);
      float e1 = EXP2(st[ct][1]);
      float e2 = EXP2(st[ct][2]);
      float e3 = EXP2(st[ct][3]);
      rsum += (e0 + e1) + (e2 + e3);
      uint2 pk;
      pk.x = pack2(e0, e1);
      pk.y = pack2(e2, e3);
      *(uint2*)(Pw + ln * 136 + ct * 16 + quad * 4) = pk;
    }
    // O += P V : P from own-LDS, V^T frags straight from global
    bf16x8 ap[4];
#pragma unroll
    for (int kt = 0; kt < 4; kt++)
      ap[kt] = ld_frag16(Pw + ln * 136 + kt * 32 + quad * 8);
#pragma unroll
    for (int dt = 0; dt < 4; dt++) {
      const u16* vr = vg + (long)(dt * 16 + ln) * NSEQ + kv * 128 + quad * 8;
#pragma unroll
      for (int kt = 0; kt < 4; kt++) {
        bf16x8 bv = ld_frag16(vr + kt * 32);
        o[dt] = mfma16(ap[kt], bv, o[dt]);
      }
    }
  }
  // row-sum reduce across quads; lane ln then holds full sum for q-row ln
  rsum += __shfl_xor(rsum, 16);
  rsum += __shfl_xor(rsum, 32);
#pragma unroll
  for (int r = 0; r < 4; r++) {
    float inv = 1.0f / __shfl(rsum, quad * 4 + r);
    int n = qrow0 + quad * 4 + r;
    long base = ((long)(b * NSEQ + n) * HH + h) * DD;
#pragma unroll
    for (int dt = 0; dt < 4; dt++)
      ob[base + dt * 16 + ln] = f2b(o[dt][r] * inv);
  }
}

// ---------------- GEMM2: out = o @ w_proj + b_proj (fp32 out) ----------------
__launch_bounds__(256, 3)
__global__ void gemm_proj(const u16* __restrict__ A, const u16* __restrict__ BT,
                          const float* __restrict__ bias, float* __restrict__ out) {
  const int Kd = CDIM;
  __shared__ u16 As[128 * 64];
  __shared__ u16 Bs[128 * 64];
  int t = threadIdx.x;
  int lane = t & 63, wave = t >> 6;
  int ln = lane & 15, quad = lane >> 4;
  int bm = blockIdx.x % 64, bn = blockIdx.x / 64;
  int wm = (wave >> 1) * 64, wn = (wave & 1) * 64;
  int r8 = t >> 3;
  int cb = (t & 7) * 8;
  const u16* aB = A + (long)(bm * 128) * Kd + cb;
  const u16* bB = BT + (long)(bn * 128) * Kd + cb;
  f32x4 acc[4][4] = {};
  for (int kt = 0; kt < Kd / 64; kt++) {
    __syncthreads();
#pragma unroll
    for (int c = 0; c < 4; c++) {
      int row = c * 32 + r8;
      async16(aB + (long)row * Kd + kt * 64, As + row * 64 + cb);
      async16(bB + (long)row * Kd + kt * 64, Bs + row * 64 + cb);
    }
    __syncthreads();
#pragma unroll
    for (int kk = 0; kk < 2; kk++) {
      bf16x8 af[4], bfv[4];
#pragma unroll
      for (int mt = 0; mt < 4; mt++)
        af[mt] = ld_frag16(As + (wm + mt * 16 + ln) * 64 + kk * 32 + quad * 8);
#pragma unroll
      for (int nt = 0; nt < 4; nt++)
        bfv[nt] = ld_frag16(Bs + (wn + nt * 16 + ln) * 64 + kk * 32 + quad * 8);
#pragma unroll
      for (int mt = 0; mt < 4; mt++)
#pragma unroll
        for (int nt = 0; nt < 4; nt++)
          acc[mt][nt] = mfma16(af[mt], bfv[nt], acc[mt][nt]);
    }
  }
#pragma unroll
  for (int mt = 0; mt < 4; mt++)
#pragma unroll
    for (int nt = 0; nt < 4; nt++) {
      int col = bn * 128 + wn + nt * 16 + ln;
      float bvx = bias[col];
#pragma unroll
      for (int r = 0; r < 4; r++) {
        int m = bm * 128 + wm + mt * 16 + quad * 4 + r;
        out[(long)m * CDIM + col] = acc[mt][nt][r] + bvx;
      }
    }
}

extern "C" void kernel_launch(void* const* d_in, const int* in_sizes, int n_in,
                              void* d_out, int out_size, void* d_ws, size_t ws_size,
                              hipStream_t stream) {
  const float* x = (const float*)d_in[0];
  const float* w_qkv = (const float*)d_in[1];
  const float* b_qkv = (const float*)d_in[2];
  const float* g_q = (const float*)d_in[3];
  const float* g_k = (const float*)d_in[4];
  const float* w_proj = (const float*)d_in[5];
  const float* b_proj = (const float*)d_in[6];
  float* out = (float*)d_out;

  char* ws = (char*)d_ws;
  const size_t MB = 1024 * 1024;
  u16* xb = (u16*)ws;                 // 16 MB, reused as o after gemm_qkv
  u16* wqkvT = (u16*)(ws + 16 * MB);  // 6 MB
  u16* wprojT = (u16*)(ws + 22 * MB); // 2 MB
  u16* qb = (u16*)(ws + 24 * MB);     // 16 MB
  u16* kb = (u16*)(ws + 40 * MB);     // 16 MB
  u16* vtb = (u16*)(ws + 56 * MB);    // 16 MB  (V transposed [B,H,D,N])
  u16* ob = xb;

  cvt_x<<<4096, 256, 0, stream>>>(x, xb);
  cvt_wT<<<(1024 / 32) * (3072 / 32), 256, 0, stream>>>(w_qkv, wqkvT, CDIM, 3 * CDIM);
  cvt_wT<<<(1024 / 32) * (1024 / 32), 256, 0, stream>>>(w_proj, wprojT, CDIM, CDIM);
  gemm_qkv<<<64 * 24, 256, 0, stream>>>(xb, wqkvT, b_qkv, g_q, g_k, qb, kb, vtb);
  attn<<<64 * 32, 256, 0, stream>>>(qb, kb, vtb, ob);
  gemm_proj<<<64 * 8, 256, 0, stream>>>(ob, wprojT, b_proj, out);
}

// Round 5
// 342.971 us; speedup vs baseline: 1.8769x; 1.8769x over previous
//
#include <hip/hip_runtime.h>

#define HH 16
#define DD 64
#define BBATCH 4
#define NSEQ 2048
#define CDIM 1024
#define EPSLN 1e-6f

typedef __bf16 bf16x8 __attribute__((ext_vector_type(8)));
typedef float f32x4 __attribute__((ext_vector_type(4)));
typedef short s16x4 __attribute__((ext_vector_type(4)));
typedef short s16x8 __attribute__((ext_vector_type(8)));
typedef unsigned short u16;

__device__ inline u16 f2b(float f) {  // RNE
  unsigned u = __builtin_bit_cast(unsigned, f);
  u += 0x7fffu + ((u >> 16) & 1u);
  return (u16)(u >> 16);
}
// pack 2 floats -> 2 bf16 (round-half-up; cheap)
__device__ inline unsigned pack2(float a, float b) {
  unsigned ua = __builtin_bit_cast(unsigned, a);
  unsigned ub = __builtin_bit_cast(unsigned, b);
  return ((ua + 0x8000u) >> 16) | ((ub + 0x8000u) & 0xffff0000u);
}
#if __has_builtin(__builtin_amdgcn_exp2f)
#define EXP2(x) __builtin_amdgcn_exp2f(x)
#else
#define EXP2(x) __expf((x)*0.6931471805599453f)
#endif

__device__ inline bf16x8 ld_frag16(const u16* p) {
  s16x8 v = *(const s16x8*)p;
  return __builtin_bit_cast(bf16x8, v);
}
__device__ inline f32x4 mfma16(bf16x8 a, bf16x8 b, f32x4 c) {
  return __builtin_amdgcn_mfma_f32_16x16x32_bf16(a, b, c, 0, 0, 0);
}
// async global->LDS, 16B per lane (lds dst linear in lane: base + lane*16B)
__device__ inline void async16(const u16* g, u16* l) {
  __builtin_amdgcn_global_load_lds(
      (const __attribute__((address_space(1))) void*)g,
      (__attribute__((address_space(3))) void*)l, 16, 0, 0);
}

// ---------------- convert x -> bf16 ----------------
__global__ void cvt_x(const float* __restrict__ x, u16* __restrict__ xb) {
  long i = ((long)blockIdx.x * 256 + threadIdx.x) * 8;
  float4 a = *(const float4*)(x + i);
  float4 b = *(const float4*)(x + i + 4);
  u16 r[8];
  r[0] = f2b(a.x); r[1] = f2b(a.y); r[2] = f2b(a.z); r[3] = f2b(a.w);
  r[4] = f2b(b.x); r[5] = f2b(b.y); r[6] = f2b(b.z); r[7] = f2b(b.w);
  *(s16x8*)(xb + i) = *(s16x8*)r;
}

// ---------------- transpose + convert weight: w [K][N] f32 -> wT [N][K] bf16 ----------------
__global__ void cvt_wT(const float* __restrict__ w, u16* __restrict__ wT, int K, int N) {
  __shared__ float tile[32][33];
  int nt = N / 32;
  int bn = blockIdx.x % nt, bk = blockIdx.x / nt;
  int tx = threadIdx.x % 32, ty = threadIdx.x / 32;
  int k0 = bk * 32, n0 = bn * 32;
  for (int j = 0; j < 4; j++)
    tile[ty + 8 * j][tx] = w[(long)(k0 + ty + 8 * j) * N + n0 + tx];
  __syncthreads();
  for (int j = 0; j < 4; j++)
    wT[(long)(n0 + ty + 8 * j) * K + k0 + tx] = f2b(tile[tx][ty + 8 * j]);
}

// ---------------- GEMM1: qkv = x @ w_qkv + b, fused per-head LN on q/k.
//  q,k -> [B,H,N,D] bf16 (q scaled by D^-0.5 * log2e);  v -> TRANSPOSED [B,H,D,N] bf16
__launch_bounds__(256, 3)
__global__ void gemm_qkv(const u16* __restrict__ A, const u16* __restrict__ BT,
                         const float* __restrict__ bias,
                         const float* __restrict__ gq, const float* __restrict__ gk,
                         u16* __restrict__ qb, u16* __restrict__ kb, u16* __restrict__ vtb) {
  const int Kd = CDIM;
  __shared__ u16 As[128 * 64];
  __shared__ u16 Bs[128 * 64];
  int t = threadIdx.x;
  int lane = t & 63, wave = t >> 6;
  int ln = lane & 15, quad = lane >> 4;
  int bm = blockIdx.x % 64, bn = blockIdx.x / 64;
  int wm = (wave >> 1) * 64, wn = (wave & 1) * 64;
  int r8 = t >> 3;
  int cb = (t & 7) * 8;
  const u16* aB = A + (long)(bm * 128) * Kd + cb;
  const u16* bB = BT + (long)(bn * 128) * Kd + cb;
  f32x4 acc[4][4] = {};
  for (int kt = 0; kt < Kd / 64; kt++) {
    __syncthreads();
#pragma unroll
    for (int c = 0; c < 4; c++) {
      int row = c * 32 + r8;
      async16(aB + (long)row * Kd + kt * 64, As + row * 64 + cb);
      async16(bB + (long)row * Kd + kt * 64, Bs + row * 64 + cb);
    }
    __syncthreads();
#pragma unroll
    for (int kk = 0; kk < 2; kk++) {
      bf16x8 af[4], bfv[4];
#pragma unroll
      for (int mt = 0; mt < 4; mt++)
        af[mt] = ld_frag16(As + (wm + mt * 16 + ln) * 64 + kk * 32 + quad * 8);
#pragma unroll
      for (int nt = 0; nt < 4; nt++)
        bfv[nt] = ld_frag16(Bs + (wn + nt * 16 + ln) * 64 + kk * 32 + quad * 8);
#pragma unroll
      for (int mt = 0; mt < 4; mt++)
#pragma unroll
        for (int nt = 0; nt < 4; nt++)
          acc[mt][nt] = mfma16(af[mt], bfv[nt], acc[mt][nt]);
    }
  }
  // ---- epilogue ----
  int tq = bn >> 3;
  int colbase = bn * 128 + wn;
  int h = (colbase >> 6) & 15;
  int mbase = bm * 128 + wm;
  float bv[4];
#pragma unroll
  for (int nt = 0; nt < 4; nt++) bv[nt] = bias[colbase + nt * 16 + ln];
  if (tq == 2) {
#pragma unroll
    for (int mt = 0; mt < 4; mt++) {
      int m0 = mbase + mt * 16 + quad * 4;
      int b = m0 >> 11, n0 = m0 & 2047;
#pragma unroll
      for (int nt = 0; nt < 4; nt++) {
        int d = nt * 16 + ln;
        u16 pk[4];
#pragma unroll
        for (int r = 0; r < 4; r++) pk[r] = f2b(acc[mt][nt][r] + bv[nt]);
        *(s16x4*)(vtb + ((long)((b * HH + h) * DD + d)) * NSEQ + n0) = *(s16x4*)pk;
      }
    }
  } else {
    const float* g = (tq == 0) ? gq : gk;
    float extra = (tq == 0) ? 0.125f * 1.4426950408889634f : 1.0f;
    u16* dst = (tq == 0) ? qb : kb;
    float gv[4];
#pragma unroll
    for (int nt = 0; nt < 4; nt++) gv[nt] = g[nt * 16 + ln] * extra;
#pragma unroll
    for (int mt = 0; mt < 4; mt++)
#pragma unroll
      for (int r = 0; r < 4; r++) {
        float vv[4];
        float s1 = 0.f, s2 = 0.f;
#pragma unroll
        for (int nt = 0; nt < 4; nt++) {
          vv[nt] = acc[mt][nt][r] + bv[nt];
          s1 += vv[nt];
          s2 += vv[nt] * vv[nt];
        }
#pragma unroll
        for (int m = 1; m < 16; m <<= 1) {
          s1 += __shfl_xor(s1, m);
          s2 += __shfl_xor(s2, m);
        }
        float mu = s1 * (1.0f / 64.0f);
        float var = s2 * (1.0f / 64.0f) - mu * mu;
        float rstd = rsqrtf(var + EPSLN);
        int m = mbase + mt * 16 + quad * 4 + r;
        int b = m >> 11, n = m & 2047;
        long base = ((long)((b * HH + h) * NSEQ + n)) * DD;
#pragma unroll
        for (int nt = 0; nt < 4; nt++)
          dst[base + nt * 16 + ln] = f2b((vv[nt] - mu) * rstd * gv[nt]);
      }
  }
}

// ---------------- flash attention v4: K/V^T staged to LDS via global_load_lds,
//  128 q per block (4 waves x 32q), S^T = K q^T, exp2, P wave-private in LDS
//  with XOR bank swizzle, PV from LDS. 2 barriers/iter. ----------------
__launch_bounds__(256, 2)
__global__ void attn(const u16* __restrict__ qb, const u16* __restrict__ kb,
                     const u16* __restrict__ vtb, u16* __restrict__ ob) {
  __shared__ u16 smem[32768];            // 64 KB exactly
  u16* Ks = smem;                        // [128][64]  16 KB
  u16* Vs = smem + 8192;                 // [64][128]  16 KB (V^T: [d][k])
  u16* Pl = smem + 16384;                // 4 waves x 2 qf x [16][128]  32 KB
  int t = threadIdx.x, lane = t & 63, wave = t >> 6;
  int ln = lane & 15, quad = lane >> 4;
  // XCD swizzle: 8 consecutive bh per XCD (K+V working set = 4 MB = one L2)
  int g = blockIdx.x;
  int bh = (g & 7) * 8 + ((g >> 3) & 7);
  int qblk = g >> 6;                     // 0..15, 128 q-rows each
  int b = bh >> 4, h = bh & 15;
  const u16* qg = qb + (long)bh * NSEQ * DD;
  const u16* kg = kb + (long)bh * NSEQ * DD;
  const u16* vg = vtb + (long)bh * DD * NSEQ;
  int qrow0 = qblk * 128 + wave * 32;
  bf16x8 bq[2][2];
#pragma unroll
  for (int qf = 0; qf < 2; qf++)
#pragma unroll
    for (int kk = 0; kk < 2; kk++)
      bq[qf][kk] = ld_frag16(qg + (long)(qrow0 + qf * 16 + ln) * DD + kk * 32 + quad * 8);
  f32x4 o[2][4] = {};
  float rs[2] = {0.f, 0.f};
  u16* Pw0 = Pl + wave * 4096;           // 2 x 16*128 u16
  u16* Pw1 = Pw0 + 2048;
  int psw = (ln & 7) * 16;               // XOR swizzle (u16 units, preserves 16B groups)
  for (int kv = 0; kv < NSEQ / 128; kv++) {
    __syncthreads();
    // stage K tile [128][64]
    long kbase = (long)kv * 128 * DD;
#pragma unroll
    for (int c = 0; c < 4; c++) {
      int off = (c * 32 + wave * 8) * 64 + lane * 8;
      async16(kg + kbase + off, Ks + off);
    }
    // stage V^T tile [64][128] from [B,H,D,N]
#pragma unroll
    for (int c = 0; c < 4; c++) {
      int drow = c * 16 + wave * 4;
      async16(vg + (long)(drow + (lane >> 4)) * NSEQ + kv * 128 + (lane & 15) * 8,
              Vs + drow * 128 + lane * 8);
    }
    __syncthreads();
    // S^T: ct-outer (K-frag read once), qf-inner; exp+pack immediately
#pragma unroll
    for (int ct = 0; ct < 8; ct++) {
      const u16* ka = Ks + (ct * 16 + ln) * 64 + quad * 8;
      bf16x8 k0 = ld_frag16(ka);
      bf16x8 k1 = ld_frag16(ka + 32);
      f32x4 z0 = {}, z1 = {};
      z0 = mfma16(k0, bq[0][0], z0);
      z0 = mfma16(k1, bq[0][1], z0);
      z1 = mfma16(k0, bq[1][0], z1);
      z1 = mfma16(k1, bq[1][1], z1);
      int poff = ln * 128 + ((ct * 16 + quad * 4) ^ psw);
      {
        float e0 = EXP2(z0[0]), e1 = EXP2(z0[1]), e2 = EXP2(z0[2]), e3 = EXP2(z0[3]);
        rs[0] += (e0 + e1) + (e2 + e3);
        uint2 pk; pk.x = pack2(e0, e1); pk.y = pack2(e2, e3);
        *(uint2*)(Pw0 + poff) = pk;
      }
      {
        float e0 = EXP2(z1[0]), e1 = EXP2(z1[1]), e2 = EXP2(z1[2]), e3 = EXP2(z1[3]);
        rs[1] += (e0 + e1) + (e2 + e3);
        uint2 pk; pk.x = pack2(e0, e1); pk.y = pack2(e2, e3);
        *(uint2*)(Pw1 + poff) = pk;
      }
    }
    // read P back as A-frags (same wave wrote it; lgkmcnt only)
    bf16x8 pA[2][4];
#pragma unroll
    for (int kt = 0; kt < 4; kt++) {
      int poff = ln * 128 + ((kt * 32 + quad * 8) ^ psw);
      pA[0][kt] = ld_frag16(Pw0 + poff);
      pA[1][kt] = ld_frag16(Pw1 + poff);
    }
    // O += P V (V-frag read once, used by both qf)
#pragma unroll
    for (int dt = 0; dt < 4; dt++) {
      const u16* vr = Vs + (dt * 16 + ln) * 128 + quad * 8;
#pragma unroll
      for (int kt = 0; kt < 4; kt++) {
        bf16x8 vv = ld_frag16(vr + kt * 32);
        o[0][dt] = mfma16(pA[0][kt], vv, o[0][dt]);
        o[1][dt] = mfma16(pA[1][kt], vv, o[1][dt]);
      }
    }
  }
  // epilogue: normalize and store [B,N,H,D]
#pragma unroll
  for (int qf = 0; qf < 2; qf++) {
    float r2 = rs[qf];
    r2 += __shfl_xor(r2, 16);
    r2 += __shfl_xor(r2, 32);
#pragma unroll
    for (int r = 0; r < 4; r++) {
      float inv = 1.0f / __shfl(r2, quad * 4 + r);
      int n = qrow0 + qf * 16 + quad * 4 + r;
      long base = ((long)(b * NSEQ + n) * HH + h) * DD;
#pragma unroll
      for (int dt = 0; dt < 4; dt++)
        ob[base + dt * 16 + ln] = f2b(o[qf][dt][r] * inv);
    }
  }
}

// ---------------- GEMM2: out = o @ w_proj + b_proj (fp32 out) ----------------
__launch_bounds__(256, 3)
__global__ void gemm_proj(const u16* __restrict__ A, const u16* __restrict__ BT,
                          const float* __restrict__ bias, float* __restrict__ out) {
  const int Kd = CDIM;
  __shared__ u16 As[128 * 64];
  __shared__ u16 Bs[128 * 64];
  int t = threadIdx.x;
  int lane = t & 63, wave = t >> 6;
  int ln = lane & 15, quad = lane >> 4;
  int bm = blockIdx.x % 64, bn = blockIdx.x / 64;
  int wm = (wave >> 1) * 64, wn = (wave & 1) * 64;
  int r8 = t >> 3;
  int cb = (t & 7) * 8;
  const u16* aB = A + (long)(bm * 128) * Kd + cb;
  const u16* bB = BT + (long)(bn * 128) * Kd + cb;
  f32x4 acc[4][4] = {};
  for (int kt = 0; kt < Kd / 64; kt++) {
    __syncthreads();
#pragma unroll
    for (int c = 0; c < 4; c++) {
      int row = c * 32 + r8;
      async16(aB + (long)row * Kd + kt * 64, As + row * 64 + cb);
      async16(bB + (long)row * Kd + kt * 64, Bs + row * 64 + cb);
    }
    __syncthreads();
#pragma unroll
    for (int kk = 0; kk < 2; kk++) {
      bf16x8 af[4], bfv[4];
#pragma unroll
      for (int mt = 0; mt < 4; mt++)
        af[mt] = ld_frag16(As + (wm + mt * 16 + ln) * 64 + kk * 32 + quad * 8);
#pragma unroll
      for (int nt = 0; nt < 4; nt++)
        bfv[nt] = ld_frag16(Bs + (wn + nt * 16 + ln) * 64 + kk * 32 + quad * 8);
#pragma unroll
      for (int mt = 0; mt < 4; mt++)
#pragma unroll
        for (int nt = 0; nt < 4; nt++)
          acc[mt][nt] = mfma16(af[mt], bfv[nt], acc[mt][nt]);
    }
  }
#pragma unroll
  for (int mt = 0; mt < 4; mt++)
#pragma unroll
    for (int nt = 0; nt < 4; nt++) {
      int col = bn * 128 + wn + nt * 16 + ln;
      float bvx = bias[col];
#pragma unroll
      for (int r = 0; r < 4; r++) {
        int m = bm * 128 + wm + mt * 16 + quad * 4 + r;
        out[(long)m * CDIM + col] = acc[mt][nt][r] + bvx;
      }
    }
}

extern "C" void kernel_launch(void* const* d_in, const int* in_sizes, int n_in,
                              void* d_out, int out_size, void* d_ws, size_t ws_size,
                              hipStream_t stream) {
  const float* x = (const float*)d_in[0];
  const float* w_qkv = (const float*)d_in[1];
  const float* b_qkv = (const float*)d_in[2];
  const float* g_q = (const float*)d_in[3];
  const float* g_k = (const float*)d_in[4];
  const float* w_proj = (const float*)d_in[5];
  const float* b_proj = (const float*)d_in[6];
  float* out = (float*)d_out;

  char* ws = (char*)d_ws;
  const size_t MB = 1024 * 1024;
  u16* xb = (u16*)ws;                 // 16 MB, reused as o after gemm_qkv
  u16* wqkvT = (u16*)(ws + 16 * MB);  // 6 MB
  u16* wprojT = (u16*)(ws + 22 * MB); // 2 MB
  u16* qb = (u16*)(ws + 24 * MB);     // 16 MB
  u16* kb = (u16*)(ws + 40 * MB);     // 16 MB
  u16* vtb = (u16*)(ws + 56 * MB);    // 16 MB  (V transposed [B,H,D,N])
  u16* ob = xb;

  cvt_x<<<4096, 256, 0, stream>>>(x, xb);
  cvt_wT<<<(1024 / 32) * (3072 / 32), 256, 0, stream>>>(w_qkv, wqkvT, CDIM, 3 * CDIM);
  cvt_wT<<<(1024 / 32) * (1024 / 32), 256, 0, stream>>>(w_proj, wprojT, CDIM, CDIM);
  gemm_qkv<<<64 * 24, 256, 0, stream>>>(xb, wqkvT, b_qkv, g_q, g_k, qb, kb, vtb);
  attn<<<64 * 16, 256, 0, stream>>>(qb, kb, vtb, ob);
  gemm_proj<<<64 * 8, 256, 0, stream>>>(ob, wprojT, b_proj, out);
}

// Round 6
// 298.140 us; speedup vs baseline: 2.1592x; 1.1504x over previous
//
#include <hip/hip_runtime.h>

#define HH 16
#define DD 64
#define BBATCH 4
#define NSEQ 2048
#define CDIM 1024
#define EPSLN 1e-6f

typedef __bf16 bf16x8 __attribute__((ext_vector_type(8)));
typedef float f32x4 __attribute__((ext_vector_type(4)));
typedef short s16x4 __attribute__((ext_vector_type(4)));
typedef short s16x8 __attribute__((ext_vector_type(8)));
typedef unsigned short u16;

__device__ inline u16 f2b(float f) {  // RNE
  unsigned u = __builtin_bit_cast(unsigned, f);
  u += 0x7fffu + ((u >> 16) & 1u);
  return (u16)(u >> 16);
}
__device__ inline unsigned pack2(float a, float b) {  // round-half-up bf16 pair
  unsigned ua = __builtin_bit_cast(unsigned, a);
  unsigned ub = __builtin_bit_cast(unsigned, b);
  return ((ua + 0x8000u) >> 16) | ((ub + 0x8000u) & 0xffff0000u);
}
#if __has_builtin(__builtin_amdgcn_exp2f)
#define EXP2(x) __builtin_amdgcn_exp2f(x)
#else
#define EXP2(x) __expf((x)*0.6931471805599453f)
#endif

__device__ inline bf16x8 ld_frag16(const u16* p) {
  s16x8 v = *(const s16x8*)p;
  return __builtin_bit_cast(bf16x8, v);
}
__device__ inline f32x4 mfma16(bf16x8 a, bf16x8 b, f32x4 c) {
  return __builtin_amdgcn_mfma_f32_16x16x32_bf16(a, b, c, 0, 0, 0);
}
// async global->LDS, 16B per lane (lds dst linear in lane: base + lane*16B)
__device__ inline void async16(const u16* g, u16* l) {
  __builtin_amdgcn_global_load_lds(
      (const __attribute__((address_space(1))) void*)g,
      (__attribute__((address_space(3))) void*)l, 16, 0, 0);
}

// ---------------- convert x -> bf16 ----------------
__global__ void cvt_x(const float* __restrict__ x, u16* __restrict__ xb) {
  long i = ((long)blockIdx.x * 256 + threadIdx.x) * 8;
  float4 a = *(const float4*)(x + i);
  float4 b = *(const float4*)(x + i + 4);
  u16 r[8];
  r[0] = f2b(a.x); r[1] = f2b(a.y); r[2] = f2b(a.z); r[3] = f2b(a.w);
  r[4] = f2b(b.x); r[5] = f2b(b.y); r[6] = f2b(b.z); r[7] = f2b(b.w);
  *(s16x8*)(xb + i) = *(s16x8*)r;
}

// ---------------- transpose + convert weight: w [K][N] f32 -> wT [N][K] bf16 ----------------
__global__ void cvt_wT(const float* __restrict__ w, u16* __restrict__ wT, int K, int N) {
  __shared__ float tile[32][33];
  int nt = N / 32;
  int bn = blockIdx.x % nt, bk = blockIdx.x / nt;
  int tx = threadIdx.x % 32, ty = threadIdx.x / 32;
  int k0 = bk * 32, n0 = bn * 32;
  for (int j = 0; j < 4; j++)
    tile[ty + 8 * j][tx] = w[(long)(k0 + ty + 8 * j) * N + n0 + tx];
  __syncthreads();
  for (int j = 0; j < 4; j++)
    wT[(long)(n0 + ty + 8 * j) * K + k0 + tx] = f2b(tile[tx][ty + 8 * j]);
}

// ---------------- GEMM1: qkv = x @ w_qkv + b, fused per-head LN on q/k.
//  LDS rows of 64 u16 = 8 chunks of 16B; stored chunk s of row r holds logical
//  chunk s^(r&7) (swizzle applied on DMA source) -> conflict-free b128 reads.
__launch_bounds__(256, 3)
__global__ void gemm_qkv(const u16* __restrict__ A, const u16* __restrict__ BT,
                         const float* __restrict__ bias,
                         const float* __restrict__ gq, const float* __restrict__ gk,
                         u16* __restrict__ qb, u16* __restrict__ kb, u16* __restrict__ vtb) {
  const int Kd = CDIM;
  __shared__ u16 As[128 * 64];
  __shared__ u16 Bs[128 * 64];
  int t = threadIdx.x;
  int lane = t & 63, wave = t >> 6;
  int ln = lane & 15, quad = lane >> 4;
  int bm = blockIdx.x % 64, bn = blockIdx.x / 64;
  int wm = (wave >> 1) * 64, wn = (wave & 1) * 64;
  int r8 = t >> 3;                      // staged row-within-block 0..31
  int cb = (t & 7) * 8;                 // stored chunk offset (u16)
  int cg = (((t & 7) ^ (r8 & 7)) * 8);  // logical chunk offset for global src
  int swl = ln & 7;                     // read-side swizzle key
  const u16* aB = A + (long)(bm * 128) * Kd + cg;
  const u16* bB = BT + (long)(bn * 128) * Kd + cg;
  f32x4 acc[4][4] = {};
  for (int kt = 0; kt < Kd / 64; kt++) {
    __syncthreads();
#pragma unroll
    for (int c = 0; c < 4; c++) {
      int row = c * 32 + r8;
      async16(aB + (long)row * Kd + kt * 64, As + row * 64 + cb);
      async16(bB + (long)row * Kd + kt * 64, Bs + row * 64 + cb);
    }
    __syncthreads();
#pragma unroll
    for (int kk = 0; kk < 2; kk++) {
      bf16x8 af[4], bfv[4];
#pragma unroll
      for (int mt = 0; mt < 4; mt++)
        af[mt] = ld_frag16(As + (wm + mt * 16 + ln) * 64 + (((kk * 4 + quad) ^ swl) * 8));
#pragma unroll
      for (int nt = 0; nt < 4; nt++)
        bfv[nt] = ld_frag16(Bs + (wn + nt * 16 + ln) * 64 + (((kk * 4 + quad) ^ swl) * 8));
#pragma unroll
      for (int mt = 0; mt < 4; mt++)
#pragma unroll
        for (int nt = 0; nt < 4; nt++)
          acc[mt][nt] = mfma16(af[mt], bfv[nt], acc[mt][nt]);
    }
  }
  // ---- epilogue ----
  int tq = bn >> 3;
  int colbase = bn * 128 + wn;
  int h = (colbase >> 6) & 15;
  int mbase = bm * 128 + wm;
  float bv[4];
#pragma unroll
  for (int nt = 0; nt < 4; nt++) bv[nt] = bias[colbase + nt * 16 + ln];
  if (tq == 2) {
#pragma unroll
    for (int mt = 0; mt < 4; mt++) {
      int m0 = mbase + mt * 16 + quad * 4;
      int b = m0 >> 11, n0 = m0 & 2047;
#pragma unroll
      for (int nt = 0; nt < 4; nt++) {
        int d = nt * 16 + ln;
        u16 pk[4];
#pragma unroll
        for (int r = 0; r < 4; r++) pk[r] = f2b(acc[mt][nt][r] + bv[nt]);
        *(s16x4*)(vtb + ((long)((b * HH + h) * DD + d)) * NSEQ + n0) = *(s16x4*)pk;
      }
    }
  } else {
    const float* g = (tq == 0) ? gq : gk;
    float extra = (tq == 0) ? 0.125f * 1.4426950408889634f : 1.0f;
    u16* dst = (tq == 0) ? qb : kb;
    float gv[4];
#pragma unroll
    for (int nt = 0; nt < 4; nt++) gv[nt] = g[nt * 16 + ln] * extra;
#pragma unroll
    for (int mt = 0; mt < 4; mt++)
#pragma unroll
      for (int r = 0; r < 4; r++) {
        float vv[4];
        float s1 = 0.f, s2 = 0.f;
#pragma unroll
        for (int nt = 0; nt < 4; nt++) {
          vv[nt] = acc[mt][nt][r] + bv[nt];
          s1 += vv[nt];
          s2 += vv[nt] * vv[nt];
        }
#pragma unroll
        for (int m = 1; m < 16; m <<= 1) {
          s1 += __shfl_xor(s1, m);
          s2 += __shfl_xor(s2, m);
        }
        float mu = s1 * (1.0f / 64.0f);
        float var = s2 * (1.0f / 64.0f) - mu * mu;
        float rstd = rsqrtf(var + EPSLN);
        int m = mbase + mt * 16 + quad * 4 + r;
        int b = m >> 11, n = m & 2047;
        long base = ((long)((b * HH + h) * NSEQ + n)) * DD;
#pragma unroll
        for (int nt = 0; nt < 4; nt++)
          dst[base + nt * 16 + ln] = f2b((vv[nt] - mu) * rstd * gv[nt]);
      }
  }
}

// ---------------- flash attention v5: like v4 but all LDS layouts bank-swizzled.
//  Ks rows 64 u16 (8 chunks), Vs rows 128 u16 (16 chunks): stored chunk s of row r
//  holds logical s^(r&7) (swizzle on DMA source). P: XOR (ln&7)*8 u16 on column.
__launch_bounds__(256, 2)
__global__ void attn(const u16* __restrict__ qb, const u16* __restrict__ kb,
                     const u16* __restrict__ vtb, u16* __restrict__ ob) {
  __shared__ u16 smem[32768];            // 64 KB
  u16* Ks = smem;                        // [128][64]  16 KB
  u16* Vs = smem + 8192;                 // [64][128]  16 KB (V^T: [d][k])
  u16* Pl = smem + 16384;                // 4 waves x 2 qf x [16][128]  32 KB
  int t = threadIdx.x, lane = t & 63, wave = t >> 6;
  int ln = lane & 15, quad = lane >> 4;
  int g = blockIdx.x;
  int bh = (g & 7) * 8 + ((g >> 3) & 7); // XCD swizzle: 8 bh per XCD
  int qblk = g >> 6;                     // 0..15, 128 q-rows each
  int b = bh >> 4, h = bh & 15;
  const u16* qg = qb + (long)bh * NSEQ * DD;
  const u16* kg = kb + (long)bh * NSEQ * DD;
  const u16* vg = vtb + (long)bh * DD * NSEQ;
  int qrow0 = qblk * 128 + wave * 32;
  bf16x8 bq[2][2];
#pragma unroll
  for (int qf = 0; qf < 2; qf++)
#pragma unroll
    for (int kk = 0; kk < 2; kk++)
      bq[qf][kk] = ld_frag16(qg + (long)(qrow0 + qf * 16 + ln) * DD + kk * 32 + quad * 8);
  f32x4 o[2][4] = {};
  float rs[2] = {0.f, 0.f};
  u16* Pw0 = Pl + wave * 4096;
  u16* Pw1 = Pw0 + 2048;
  int psw = (ln & 7) * 8;                // P column swizzle (u16 units)
  int swl = ln & 7;                      // K/V read swizzle key
  int cK = (lane & 7) ^ (lane >> 3);     // K staging: logical chunk per lane
  int rV = lane >> 4;                    // V staging: row-within-group
  for (int kv = 0; kv < NSEQ / 128; kv++) {
    __syncthreads();
    // stage K tile [128][64], swizzled
    long kbase = (long)kv * 128 * DD;
#pragma unroll
    for (int c = 0; c < 4; c++) {
      int rowb = c * 32 + wave * 8;
      async16(kg + kbase + (long)(rowb + (lane >> 3)) * 64 + cK * 8,
              Ks + rowb * 64 + lane * 8);
    }
    // stage V^T tile [64][128] from [B,H,D,N], swizzled
#pragma unroll
    for (int c = 0; c < 4; c++) {
      int drow = c * 16 + wave * 4;
      int rv = drow + rV;
      int cV = (lane & 15) ^ (rv & 7);
      async16(vg + (long)rv * NSEQ + kv * 128 + cV * 8,
              Vs + drow * 128 + lane * 8);
    }
    __syncthreads();
    // S^T: ct-outer (K-frag read once), qf-inner; exp+pack immediately
#pragma unroll
    for (int ct = 0; ct < 8; ct++) {
      const u16* ka = Ks + (ct * 16 + ln) * 64;
      bf16x8 k0 = ld_frag16(ka + ((quad ^ swl) * 8));
      bf16x8 k1 = ld_frag16(ka + (((quad + 4) ^ swl) * 8));
      f32x4 z0 = {}, z1 = {};
      z0 = mfma16(k0, bq[0][0], z0);
      z0 = mfma16(k1, bq[0][1], z0);
      z1 = mfma16(k0, bq[1][0], z1);
      z1 = mfma16(k1, bq[1][1], z1);
      int poff = ln * 128 + ((ct * 16 + quad * 4) ^ psw);
      {
        float e0 = EXP2(z0[0]), e1 = EXP2(z0[1]), e2 = EXP2(z0[2]), e3 = EXP2(z0[3]);
        rs[0] += (e0 + e1) + (e2 + e3);
        uint2 pk; pk.x = pack2(e0, e1); pk.y = pack2(e2, e3);
        *(uint2*)(Pw0 + poff) = pk;
      }
      {
        float e0 = EXP2(z1[0]), e1 = EXP2(z1[1]), e2 = EXP2(z1[2]), e3 = EXP2(z1[3]);
        rs[1] += (e0 + e1) + (e2 + e3);
        uint2 pk; pk.x = pack2(e0, e1); pk.y = pack2(e2, e3);
        *(uint2*)(Pw1 + poff) = pk;
      }
    }
    // read P back as A-frags (same wave wrote it; lgkmcnt only)
    bf16x8 pA[2][4];
#pragma unroll
    for (int kt = 0; kt < 4; kt++) {
      int poff = ln * 128 + ((kt * 32 + quad * 8) ^ psw);
      pA[0][kt] = ld_frag16(Pw0 + poff);
      pA[1][kt] = ld_frag16(Pw1 + poff);
    }
    // O += P V (V-frag read once, used by both qf)
#pragma unroll
    for (int dt = 0; dt < 4; dt++) {
      const u16* vr = Vs + (dt * 16 + ln) * 128;
#pragma unroll
      for (int kt = 0; kt < 4; kt++) {
        bf16x8 vv = ld_frag16(vr + (((4 * kt + quad) ^ swl) * 8));
        o[0][dt] = mfma16(pA[0][kt], vv, o[0][dt]);
        o[1][dt] = mfma16(pA[1][kt], vv, o[1][dt]);
      }
    }
  }
  // epilogue: normalize and store [B,N,H,D]
#pragma unroll
  for (int qf = 0; qf < 2; qf++) {
    float r2 = rs[qf];
    r2 += __shfl_xor(r2, 16);
    r2 += __shfl_xor(r2, 32);
#pragma unroll
    for (int r = 0; r < 4; r++) {
      float inv = 1.0f / __shfl(r2, quad * 4 + r);
      int n = qrow0 + qf * 16 + quad * 4 + r;
      long base = ((long)(b * NSEQ + n) * HH + h) * DD;
#pragma unroll
      for (int dt = 0; dt < 4; dt++)
        ob[base + dt * 16 + ln] = f2b(o[qf][dt][r] * inv);
    }
  }
}

// ---------------- GEMM2: out = o @ w_proj + b_proj (fp32 out), same swizzle ----------------
__launch_bounds__(256, 3)
__global__ void gemm_proj(const u16* __restrict__ A, const u16* __restrict__ BT,
                          const float* __restrict__ bias, float* __restrict__ out) {
  const int Kd = CDIM;
  __shared__ u16 As[128 * 64];
  __shared__ u16 Bs[128 * 64];
  int t = threadIdx.x;
  int lane = t & 63, wave = t >> 6;
  int ln = lane & 15, quad = lane >> 4;
  int bm = blockIdx.x % 64, bn = blockIdx.x / 64;
  int wm = (wave >> 1) * 64, wn = (wave & 1) * 64;
  int r8 = t >> 3;
  int cb = (t & 7) * 8;
  int cg = (((t & 7) ^ (r8 & 7)) * 8);
  int swl = ln & 7;
  const u16* aB = A + (long)(bm * 128) * Kd + cg;
  const u16* bB = BT + (long)(bn * 128) * Kd + cg;
  f32x4 acc[4][4] = {};
  for (int kt = 0; kt < Kd / 64; kt++) {
    __syncthreads();
#pragma unroll
    for (int c = 0; c < 4; c++) {
      int row = c * 32 + r8;
      async16(aB + (long)row * Kd + kt * 64, As + row * 64 + cb);
      async16(bB + (long)row * Kd + kt * 64, Bs + row * 64 + cb);
    }
    __syncthreads();
#pragma unroll
    for (int kk = 0; kk < 2; kk++) {
      bf16x8 af[4], bfv[4];
#pragma unroll
      for (int mt = 0; mt < 4; mt++)
        af[mt] = ld_frag16(As + (wm + mt * 16 + ln) * 64 + (((kk * 4 + quad) ^ swl) * 8));
#pragma unroll
      for (int nt = 0; nt < 4; nt++)
        bfv[nt] = ld_frag16(Bs + (wn + nt * 16 + ln) * 64 + (((kk * 4 + quad) ^ swl) * 8));
#pragma unroll
      for (int mt = 0; mt < 4; mt++)
#pragma unroll
        for (int nt = 0; nt < 4; nt++)
          acc[mt][nt] = mfma16(af[mt], bfv[nt], acc[mt][nt]);
    }
  }
#pragma unroll
  for (int mt = 0; mt < 4; mt++)
#pragma unroll
    for (int nt = 0; nt < 4; nt++) {
      int col = bn * 128 + wn + nt * 16 + ln;
      float bvx = bias[col];
#pragma unroll
      for (int r = 0; r < 4; r++) {
        int m = bm * 128 + wm + mt * 16 + quad * 4 + r;
        out[(long)m * CDIM + col] = acc[mt][nt][r] + bvx;
      }
    }
}

extern "C" void kernel_launch(void* const* d_in, const int* in_sizes, int n_in,
                              void* d_out, int out_size, void* d_ws, size_t ws_size,
                              hipStream_t stream) {
  const float* x = (const float*)d_in[0];
  const float* w_qkv = (const float*)d_in[1];
  const float* b_qkv = (const float*)d_in[2];
  const float* g_q = (const float*)d_in[3];
  const float* g_k = (const float*)d_in[4];
  const float* w_proj = (const float*)d_in[5];
  const float* b_proj = (const float*)d_in[6];
  float* out = (float*)d_out;

  char* ws = (char*)d_ws;
  const size_t MB = 1024 * 1024;
  u16* xb = (u16*)ws;                 // 16 MB, reused as o after gemm_qkv
  u16* wqkvT = (u16*)(ws + 16 * MB);  // 6 MB
  u16* wprojT = (u16*)(ws + 22 * MB); // 2 MB
  u16* qb = (u16*)(ws + 24 * MB);     // 16 MB
  u16* kb = (u16*)(ws + 40 * MB);     // 16 MB
  u16* vtb = (u16*)(ws + 56 * MB);    // 16 MB  (V transposed [B,H,D,N])
  u16* ob = xb;

  cvt_x<<<4096, 256, 0, stream>>>(x, xb);
  cvt_wT<<<(1024 / 32) * (3072 / 32), 256, 0, stream>>>(w_qkv, wqkvT, CDIM, 3 * CDIM);
  cvt_wT<<<(1024 / 32) * (1024 / 32), 256, 0, stream>>>(w_proj, wprojT, CDIM, CDIM);
  gemm_qkv<<<64 * 24, 256, 0, stream>>>(xb, wqkvT, b_qkv, g_q, g_k, qb, kb, vtb);
  attn<<<64 * 16, 256, 0, stream>>>(qb, kb, vtb, ob);
  gemm_proj<<<64 * 8, 256, 0, stream>>>(ob, wprojT, b_proj, out);
}

// Round 7
// 272.514 us; speedup vs baseline: 2.3622x; 1.0940x over previous
//
#include <hip/hip_runtime.h>

#define HH 16
#define DD 64
#define BBATCH 4
#define NSEQ 2048
#define CDIM 1024
#define EPSLN 1e-6f

typedef __bf16 bf16x8 __attribute__((ext_vector_type(8)));
typedef float f32x4 __attribute__((ext_vector_type(4)));
typedef short s16x4 __attribute__((ext_vector_type(4)));
typedef short s16x8 __attribute__((ext_vector_type(8)));
typedef unsigned short u16;

__device__ inline u16 f2b(float f) {  // RNE
  unsigned u = __builtin_bit_cast(unsigned, f);
  u += 0x7fffu + ((u >> 16) & 1u);
  return (u16)(u >> 16);
}
// pack 2 floats -> 2 bf16 (round-half-up), 3 VALU ops via v_perm_b32
#if __has_builtin(__builtin_amdgcn_perm)
__device__ inline unsigned pack2(float a, float b) {
  unsigned ua = __builtin_bit_cast(unsigned, a) + 0x8000u;
  unsigned ub = __builtin_bit_cast(unsigned, b) + 0x8000u;
  return __builtin_amdgcn_perm(ub, ua, 0x07060302u);
}
#else
__device__ inline unsigned pack2(float a, float b) {
  unsigned ua = __builtin_bit_cast(unsigned, a);
  unsigned ub = __builtin_bit_cast(unsigned, b);
  return ((ua + 0x8000u) >> 16) | ((ub + 0x8000u) & 0xffff0000u);
}
#endif
#if __has_builtin(__builtin_amdgcn_exp2f)
#define EXP2(x) __builtin_amdgcn_exp2f(x)
#else
#define EXP2(x) __expf((x)*0.6931471805599453f)
#endif

__device__ inline bf16x8 ld_frag16(const u16* p) {
  s16x8 v = *(const s16x8*)p;
  return __builtin_bit_cast(bf16x8, v);
}
__device__ inline f32x4 mfma16(bf16x8 a, bf16x8 b, f32x4 c) {
  return __builtin_amdgcn_mfma_f32_16x16x32_bf16(a, b, c, 0, 0, 0);
}
// async global->LDS, 16B per lane (lds dst linear in lane: base + lane*16B)
__device__ inline void async16(const u16* g, u16* l) {
  __builtin_amdgcn_global_load_lds(
      (const __attribute__((address_space(1))) void*)g,
      (__attribute__((address_space(3))) void*)l, 16, 0, 0);
}

// ---------------- convert x -> bf16 ----------------
__global__ void cvt_x(const float* __restrict__ x, u16* __restrict__ xb) {
  long i = ((long)blockIdx.x * 256 + threadIdx.x) * 8;
  float4 a = *(const float4*)(x + i);
  float4 b = *(const float4*)(x + i + 4);
  u16 r[8];
  r[0] = f2b(a.x); r[1] = f2b(a.y); r[2] = f2b(a.z); r[3] = f2b(a.w);
  r[4] = f2b(b.x); r[5] = f2b(b.y); r[6] = f2b(b.z); r[7] = f2b(b.w);
  *(s16x8*)(xb + i) = *(s16x8*)r;
}

// ---------------- transpose + convert weight: w [K][N] f32 -> wT [N][K] bf16 ----------------
__global__ void cvt_wT(const float* __restrict__ w, u16* __restrict__ wT, int K, int N) {
  __shared__ float tile[32][33];
  int nt = N / 32;
  int bn = blockIdx.x % nt, bk = blockIdx.x / nt;
  int tx = threadIdx.x % 32, ty = threadIdx.x / 32;
  int k0 = bk * 32, n0 = bn * 32;
  for (int j = 0; j < 4; j++)
    tile[ty + 8 * j][tx] = w[(long)(k0 + ty + 8 * j) * N + n0 + tx];
  __syncthreads();
  for (int j = 0; j < 4; j++)
    wT[(long)(n0 + ty + 8 * j) * K + k0 + tx] = f2b(tile[tx][ty + 8 * j]);
}

// ---------------- GEMM1: qkv = x @ w_qkv + b, fused per-head LN on q/k.
//  LDS rows of 64 u16 = 8 chunks of 16B; stored chunk s of row r holds logical
//  chunk s^(r&7) (swizzle applied on DMA source) -> conflict-free b128 reads.
__launch_bounds__(256, 3)
__global__ void gemm_qkv(const u16* __restrict__ A, const u16* __restrict__ BT,
                         const float* __restrict__ bias,
                         const float* __restrict__ gq, const float* __restrict__ gk,
                         u16* __restrict__ qb, u16* __restrict__ kb, u16* __restrict__ vtb) {
  const int Kd = CDIM;
  __shared__ u16 As[128 * 64];
  __shared__ u16 Bs[128 * 64];
  int t = threadIdx.x;
  int lane = t & 63, wave = t >> 6;
  int ln = lane & 15, quad = lane >> 4;
  int bm = blockIdx.x % 64, bn = blockIdx.x / 64;
  int wm = (wave >> 1) * 64, wn = (wave & 1) * 64;
  int r8 = t >> 3;                      // staged row-within-block 0..31
  int cb = (t & 7) * 8;                 // stored chunk offset (u16)
  int cg = (((t & 7) ^ (r8 & 7)) * 8);  // logical chunk offset for global src
  int swl = ln & 7;                     // read-side swizzle key
  const u16* aB = A + (long)(bm * 128) * Kd + cg;
  const u16* bB = BT + (long)(bn * 128) * Kd + cg;
  f32x4 acc[4][4] = {};
  for (int kt = 0; kt < Kd / 64; kt++) {
    __syncthreads();
#pragma unroll
    for (int c = 0; c < 4; c++) {
      int row = c * 32 + r8;
      async16(aB + (long)row * Kd + kt * 64, As + row * 64 + cb);
      async16(bB + (long)row * Kd + kt * 64, Bs + row * 64 + cb);
    }
    __syncthreads();
#pragma unroll
    for (int kk = 0; kk < 2; kk++) {
      bf16x8 af[4], bfv[4];
#pragma unroll
      for (int mt = 0; mt < 4; mt++)
        af[mt] = ld_frag16(As + (wm + mt * 16 + ln) * 64 + (((kk * 4 + quad) ^ swl) * 8));
#pragma unroll
      for (int nt = 0; nt < 4; nt++)
        bfv[nt] = ld_frag16(Bs + (wn + nt * 16 + ln) * 64 + (((kk * 4 + quad) ^ swl) * 8));
#pragma unroll
      for (int mt = 0; mt < 4; mt++)
#pragma unroll
        for (int nt = 0; nt < 4; nt++)
          acc[mt][nt] = mfma16(af[mt], bfv[nt], acc[mt][nt]);
    }
  }
  // ---- epilogue ----
  int tq = bn >> 3;
  int colbase = bn * 128 + wn;
  int h = (colbase >> 6) & 15;
  int mbase = bm * 128 + wm;
  float bv[4];
#pragma unroll
  for (int nt = 0; nt < 4; nt++) bv[nt] = bias[colbase + nt * 16 + ln];
  if (tq == 2) {
#pragma unroll
    for (int mt = 0; mt < 4; mt++) {
      int m0 = mbase + mt * 16 + quad * 4;
      int b = m0 >> 11, n0 = m0 & 2047;
#pragma unroll
      for (int nt = 0; nt < 4; nt++) {
        int d = nt * 16 + ln;
        u16 pk[4];
#pragma unroll
        for (int r = 0; r < 4; r++) pk[r] = f2b(acc[mt][nt][r] + bv[nt]);
        *(s16x4*)(vtb + ((long)((b * HH + h) * DD + d)) * NSEQ + n0) = *(s16x4*)pk;
      }
    }
  } else {
    const float* g = (tq == 0) ? gq : gk;
    float extra = (tq == 0) ? 0.125f * 1.4426950408889634f : 1.0f;
    u16* dst = (tq == 0) ? qb : kb;
    float gv[4];
#pragma unroll
    for (int nt = 0; nt < 4; nt++) gv[nt] = g[nt * 16 + ln] * extra;
#pragma unroll
    for (int mt = 0; mt < 4; mt++)
#pragma unroll
      for (int r = 0; r < 4; r++) {
        float vv[4];
        float s1 = 0.f, s2 = 0.f;
#pragma unroll
        for (int nt = 0; nt < 4; nt++) {
          vv[nt] = acc[mt][nt][r] + bv[nt];
          s1 += vv[nt];
          s2 += vv[nt] * vv[nt];
        }
#pragma unroll
        for (int m = 1; m < 16; m <<= 1) {
          s1 += __shfl_xor(s1, m);
          s2 += __shfl_xor(s2, m);
        }
        float mu = s1 * (1.0f / 64.0f);
        float var = s2 * (1.0f / 64.0f) - mu * mu;
        float rstd = rsqrtf(var + EPSLN);
        int m = mbase + mt * 16 + quad * 4 + r;
        int b = m >> 11, n = m & 2047;
        long base = ((long)((b * HH + h) * NSEQ + n)) * DD;
#pragma unroll
        for (int nt = 0; nt < 4; nt++)
          dst[base + nt * 16 + ln] = f2b((vv[nt] - mu) * rstd * gv[nt]);
      }
  }
}

// ---------------- flash attention v6: 64 q-rows/wave (256 q/block), grid=512
//  (exactly 2 blocks/CU). K/V frags amortized over 4 q-frags. P wave-private,
//  split by k-half (64x64 per wave) so LDS stays 64KB. Same XOR bank swizzles.
__launch_bounds__(256, 2)
__global__ void attn(const u16* __restrict__ qb, const u16* __restrict__ kb,
                     const u16* __restrict__ vtb, u16* __restrict__ ob) {
  __shared__ u16 smem[32768];            // 64 KB
  u16* Ks = smem;                        // [128][64]  16 KB
  u16* Vs = smem + 8192;                 // [64][128]  16 KB (V^T: [d][k])
  u16* Pl = smem + 16384;                // 4 waves x [64 q][64 k]  32 KB
  int t = threadIdx.x, lane = t & 63, wave = t >> 6;
  int ln = lane & 15, quad = lane >> 4;
  int g = blockIdx.x;
  int bh = (g & 7) * 8 + ((g >> 3) & 7); // XCD swizzle: 8 bh per XCD
  int qblk = (g >> 6) & 7;               // 0..7, 256 q-rows each
  int b = bh >> 4, h = bh & 15;
  const u16* qg = qb + (long)bh * NSEQ * DD;
  const u16* kg = kb + (long)bh * NSEQ * DD;
  const u16* vg = vtb + (long)bh * DD * NSEQ;
  int qrow0 = qblk * 256 + wave * 64;
  bf16x8 bq[4][2];
#pragma unroll
  for (int qf = 0; qf < 4; qf++)
#pragma unroll
    for (int kk = 0; kk < 2; kk++)
      bq[qf][kk] = ld_frag16(qg + (long)(qrow0 + qf * 16 + ln) * DD + kk * 32 + quad * 8);
  f32x4 o[4][4] = {};
  float rs[4] = {0.f, 0.f, 0.f, 0.f};
  u16* Pw = Pl + wave * 4096;            // [64 q][64 k]
  int psw = (ln & 7) * 8;                // P column swizzle (u16 units)
  int swl = ln & 7;                      // K/V read swizzle key
  int cK = (lane & 7) ^ (lane >> 3);     // K staging: logical chunk per lane
  int rV = lane >> 4;                    // V staging: row-within-group
  for (int kv = 0; kv < NSEQ / 128; kv++) {
    __syncthreads();
    // stage K tile [128][64], swizzled
    long kbase = (long)kv * 128 * DD;
#pragma unroll
    for (int c = 0; c < 4; c++) {
      int rowb = c * 32 + wave * 8;
      async16(kg + kbase + (long)(rowb + (lane >> 3)) * 64 + cK * 8,
              Ks + rowb * 64 + lane * 8);
    }
    // stage V^T tile [64][128] from [B,H,D,N], swizzled
#pragma unroll
    for (int c = 0; c < 4; c++) {
      int drow = c * 16 + wave * 4;
      int rv = drow + rV;
      int cV = (lane & 15) ^ (rv & 7);
      async16(vg + (long)rv * NSEQ + kv * 128 + cV * 8,
              Vs + drow * 128 + lane * 8);
    }
    __syncthreads();
#pragma unroll
    for (int half = 0; half < 2; half++) {
      // S^T for this k-half: ct-outer (K-frag read once), qf-inner
#pragma unroll
      for (int ctl = 0; ctl < 4; ctl++) {
        int ct = half * 4 + ctl;
        const u16* ka = Ks + (ct * 16 + ln) * 64;
        bf16x8 k0 = ld_frag16(ka + ((quad ^ swl) * 8));
        bf16x8 k1 = ld_frag16(ka + (((quad + 4) ^ swl) * 8));
        int poffc = (ctl * 16 + quad * 4) ^ psw;
#pragma unroll
        for (int qf = 0; qf < 4; qf++) {
          f32x4 z = {};
          z = mfma16(k0, bq[qf][0], z);
          z = mfma16(k1, bq[qf][1], z);
          float e0 = EXP2(z[0]), e1 = EXP2(z[1]), e2 = EXP2(z[2]), e3 = EXP2(z[3]);
          rs[qf] += (e0 + e1) + (e2 + e3);
          uint2 pk;
          pk.x = pack2(e0, e1);
          pk.y = pack2(e2, e3);
          *(uint2*)(Pw + (qf * 16 + ln) * 64 + poffc) = pk;
        }
      }
      // O += P V for this k-half (P read by same wave; V-frag reused by 4 qf)
      bf16x8 pA[4][2];
#pragma unroll
      for (int qf = 0; qf < 4; qf++)
#pragma unroll
        for (int ktl = 0; ktl < 2; ktl++)
          pA[qf][ktl] = ld_frag16(Pw + (qf * 16 + ln) * 64 + ((ktl * 32 + quad * 8) ^ psw));
#pragma unroll
      for (int dt = 0; dt < 4; dt++) {
        const u16* vr = Vs + (dt * 16 + ln) * 128;
#pragma unroll
        for (int ktl = 0; ktl < 2; ktl++) {
          int kt = half * 2 + ktl;
          bf16x8 vv = ld_frag16(vr + (((4 * kt + quad) ^ swl) * 8));
#pragma unroll
          for (int qf = 0; qf < 4; qf++)
            o[qf][dt] = mfma16(pA[qf][ktl], vv, o[qf][dt]);
        }
      }
    }
  }
  // epilogue: normalize and store [B,N,H,D]
#pragma unroll
  for (int qf = 0; qf < 4; qf++) {
    float r2 = rs[qf];
    r2 += __shfl_xor(r2, 16);
    r2 += __shfl_xor(r2, 32);
#pragma unroll
    for (int r = 0; r < 4; r++) {
      float inv = 1.0f / __shfl(r2, quad * 4 + r);
      int n = qrow0 + qf * 16 + quad * 4 + r;
      long base = ((long)(b * NSEQ + n) * HH + h) * DD;
#pragma unroll
      for (int dt = 0; dt < 4; dt++)
        ob[base + dt * 16 + ln] = f2b(o[qf][dt][r] * inv);
    }
  }
}

// ---------------- GEMM2: out = o @ w_proj + b_proj (fp32 out), same swizzle ----------------
__launch_bounds__(256, 3)
__global__ void gemm_proj(const u16* __restrict__ A, const u16* __restrict__ BT,
                          const float* __restrict__ bias, float* __restrict__ out) {
  const int Kd = CDIM;
  __shared__ u16 As[128 * 64];
  __shared__ u16 Bs[128 * 64];
  int t = threadIdx.x;
  int lane = t & 63, wave = t >> 6;
  int ln = lane & 15, quad = lane >> 4;
  int bm = blockIdx.x % 64, bn = blockIdx.x / 64;
  int wm = (wave >> 1) * 64, wn = (wave & 1) * 64;
  int r8 = t >> 3;
  int cb = (t & 7) * 8;
  int cg = (((t & 7) ^ (r8 & 7)) * 8);
  int swl = ln & 7;
  const u16* aB = A + (long)(bm * 128) * Kd + cg;
  const u16* bB = BT + (long)(bn * 128) * Kd + cg;
  f32x4 acc[4][4] = {};
  for (int kt = 0; kt < Kd / 64; kt++) {
    __syncthreads();
#pragma unroll
    for (int c = 0; c < 4; c++) {
      int row = c * 32 + r8;
      async16(aB + (long)row * Kd + kt * 64, As + row * 64 + cb);
      async16(bB + (long)row * Kd + kt * 64, Bs + row * 64 + cb);
    }
    __syncthreads();
#pragma unroll
    for (int kk = 0; kk < 2; kk++) {
      bf16x8 af[4], bfv[4];
#pragma unroll
      for (int mt = 0; mt < 4; mt++)
        af[mt] = ld_frag16(As + (wm + mt * 16 + ln) * 64 + (((kk * 4 + quad) ^ swl) * 8));
#pragma unroll
      for (int nt = 0; nt < 4; nt++)
        bfv[nt] = ld_frag16(Bs + (wn + nt * 16 + ln) * 64 + (((kk * 4 + quad) ^ swl) * 8));
#pragma unroll
      for (int mt = 0; mt < 4; mt++)
#pragma unroll
        for (int nt = 0; nt < 4; nt++)
          acc[mt][nt] = mfma16(af[mt], bfv[nt], acc[mt][nt]);
    }
  }
#pragma unroll
  for (int mt = 0; mt < 4; mt++)
#pragma unroll
    for (int nt = 0; nt < 4; nt++) {
      int col = bn * 128 + wn + nt * 16 + ln;
      float bvx = bias[col];
#pragma unroll
      for (int r = 0; r < 4; r++) {
        int m = bm * 128 + wm + mt * 16 + quad * 4 + r;
        out[(long)m * CDIM + col] = acc[mt][nt][r] + bvx;
      }
    }
}

extern "C" void kernel_launch(void* const* d_in, const int* in_sizes, int n_in,
                              void* d_out, int out_size, void* d_ws, size_t ws_size,
                              hipStream_t stream) {
  const float* x = (const float*)d_in[0];
  const float* w_qkv = (const float*)d_in[1];
  const float* b_qkv = (const float*)d_in[2];
  const float* g_q = (const float*)d_in[3];
  const float* g_k = (const float*)d_in[4];
  const float* w_proj = (const float*)d_in[5];
  const float* b_proj = (const float*)d_in[6];
  float* out = (float*)d_out;

  char* ws = (char*)d_ws;
  const size_t MB = 1024 * 1024;
  u16* xb = (u16*)ws;                 // 16 MB, reused as o after gemm_qkv
  u16* wqkvT = (u16*)(ws + 16 * MB);  // 6 MB
  u16* wprojT = (u16*)(ws + 22 * MB); // 2 MB
  u16* qb = (u16*)(ws + 24 * MB);     // 16 MB
  u16* kb = (u16*)(ws + 40 * MB);     // 16 MB
  u16* vtb = (u16*)(ws + 56 * MB);    // 16 MB  (V transposed [B,H,D,N])
  u16* ob = xb;

  cvt_x<<<4096, 256, 0, stream>>>(x, xb);
  cvt_wT<<<(1024 / 32) * (3072 / 32), 256, 0, stream>>>(w_qkv, wqkvT, CDIM, 3 * CDIM);
  cvt_wT<<<(1024 / 32) * (1024 / 32), 256, 0, stream>>>(w_proj, wprojT, CDIM, CDIM);
  gemm_qkv<<<64 * 24, 256, 0, stream>>>(xb, wqkvT, b_qkv, g_q, g_k, qb, kb, vtb);
  attn<<<512, 256, 0, stream>>>(qb, kb, vtb, ob);
  gemm_proj<<<64 * 8, 256, 0, stream>>>(ob, wprojT, b_proj, out);
}